// Round 1
// baseline (393.431 us; speedup 1.0000x reference)
//
#include <hip/hip_runtime.h>

// ---- types / helpers -------------------------------------------------------
typedef __bf16 bf16x8 __attribute__((ext_vector_type(8)));
typedef float f32x4 __attribute__((ext_vector_type(4)));
typedef unsigned short ushortx8 __attribute__((ext_vector_type(8)));
typedef unsigned short ushortx4 __attribute__((ext_vector_type(4)));

#define DEVI static __device__ __forceinline__

DEVI unsigned short f2bf(float f) {  // round-to-nearest-even f32 -> bf16
  unsigned int u = __builtin_bit_cast(unsigned int, f);
  u += 0x7FFFu + ((u >> 16) & 1u);
  return (unsigned short)(u >> 16);
}

DEVI bf16x8 ld8(const unsigned short* p) {  // 16B vector load (global or LDS)
  return __builtin_bit_cast(bf16x8, *(const ushortx8*)p);
}

DEVI void gll16(const unsigned short* g, unsigned short* l) {  // global->LDS 16B DMA
  __builtin_amdgcn_global_load_lds((const __attribute__((address_space(1))) void*)g,
                                   (__attribute__((address_space(3))) void*)l, 16, 0, 0);
}

#define MFMA16(a, b, c) __builtin_amdgcn_mfma_f32_16x16x32_bf16(a, b, c, 0, 0, 0)

// ---- problem constants -----------------------------------------------------
// B=4, T=2048, E=1024, H=16, D=64
#define SB 4
#define ST 2048
#define SE 1024
#define SH 16
#define SD 64

// ---- f32 -> bf16 convert ---------------------------------------------------
__global__ void cvt_f32_bf16(const float* __restrict__ in, unsigned short* __restrict__ out, int n4) {
  int i = blockIdx.x * blockDim.x + threadIdx.x;
  if (i >= n4) return;
  float4 v = ((const float4*)in)[i];
  ushortx4 o;
  o.x = f2bf(v.x); o.y = f2bf(v.y); o.z = f2bf(v.z); o.w = f2bf(v.w);
  ((ushortx4*)out)[i] = o;
}

// ---- NT GEMM: C[m,n] = sum_k A[m,k]*Bw[n,k], both bf16 K-contiguous --------
// 128x128 tile, BK=64, 4 waves (2x2), each wave 64x64 (4x4 MFMA frags).
// EPI==0: plain f32 store to Cf[M,N].
// EPI==1: scatter qkv -> Q[B,H,T,D], K[B,H,T,D], VT[B,H,D,T] in bf16.
template<int EPI>
__global__ __launch_bounds__(256, 2) void gemm_nt(
    const unsigned short* __restrict__ A, const unsigned short* __restrict__ Bw,
    float* __restrict__ Cf,
    unsigned short* __restrict__ Qo, unsigned short* __restrict__ Ko,
    unsigned short* __restrict__ VTo,
    int M, int N, int K) {
  __shared__ unsigned short As[128 * 64];
  __shared__ unsigned short Bs[128 * 64];
  const int tid = threadIdx.x;
  const int lane = tid & 63;
  const int w = tid >> 6;
  const int wr = w >> 1, wc = w & 1;
  const int r16 = lane & 15, g = lane >> 4;
  const int m0 = blockIdx.y * 128, n0 = blockIdx.x * 128;

  f32x4 acc[4][4] = {};

  for (int k0 = 0; k0 < K; k0 += 64) {
    __syncthreads();
#pragma unroll
    for (int it = 0; it < 4; ++it) {  // stage A tile [128][64]
      int c = it * 256 + tid;
      int row = c >> 3, cb = (c & 7) * 8;
      gll16(A + (size_t)(m0 + row) * K + k0 + cb, As + c * 8);
    }
#pragma unroll
    for (int it = 0; it < 4; ++it) {  // stage B tile [128][64]
      int c = it * 256 + tid;
      int row = c >> 3, cb = (c & 7) * 8;
      gll16(Bw + (size_t)(n0 + row) * K + k0 + cb, Bs + c * 8);
    }
    __syncthreads();
#pragma unroll
    for (int ks = 0; ks < 2; ++ks) {
      bf16x8 af[4], bfr[4];
#pragma unroll
      for (int mt = 0; mt < 4; ++mt)
        af[mt] = ld8(&As[(wr * 64 + mt * 16 + r16) * 64 + ks * 32 + g * 8]);
#pragma unroll
      for (int nt = 0; nt < 4; ++nt)
        bfr[nt] = ld8(&Bs[(wc * 64 + nt * 16 + r16) * 64 + ks * 32 + g * 8]);
#pragma unroll
      for (int mt = 0; mt < 4; ++mt)
#pragma unroll
        for (int nt = 0; nt < 4; ++nt)
          acc[mt][nt] = MFMA16(af[mt], bfr[nt], acc[mt][nt]);
    }
  }

  // epilogue: C frag layout col = lane&15, row = (lane>>4)*4 + r
#pragma unroll
  for (int mt = 0; mt < 4; ++mt) {
#pragma unroll
    for (int nt = 0; nt < 4; ++nt) {
#pragma unroll
      for (int r = 0; r < 4; ++r) {
        int m = m0 + wr * 64 + mt * 16 + g * 4 + r;
        int n = n0 + wc * 64 + nt * 16 + r16;
        float v = acc[mt][nt][r];
        if (EPI == 0) {
          Cf[(size_t)m * N + n] = v;
        } else {
          int b = m >> 11, t = m & (ST - 1);
          int which = n >> 10, h = (n >> 6) & (SH - 1), d = n & (SD - 1);
          int bh = b * SH + h;
          unsigned short hv = f2bf(v);
          if (which == 0)
            Qo[((size_t)bh * ST + t) * SD + d] = hv;
          else if (which == 1)
            Ko[((size_t)bh * ST + t) * SD + d] = hv;
          else
            VTo[((size_t)bh * SD + d) * ST + t] = hv;
        }
      }
    }
  }
}

// ---- causal flash attention ------------------------------------------------
// grid: (T/64, B*H). 4 waves, each wave owns 16 q-rows. KV tiles of 64.
__global__ __launch_bounds__(256, 2) void attn_causal(
    const unsigned short* __restrict__ Q, const unsigned short* __restrict__ Kv,
    const unsigned short* __restrict__ VT, unsigned short* __restrict__ Y) {
  __shared__ unsigned short Ks[64 * 64];        // [t][d]
  __shared__ unsigned short Vs[64 * 64];        // [d][t]  (from VT global)
  __shared__ unsigned short Ps[4][16][72];      // per-wave P, padded stride 72

  const int tid = threadIdx.x;
  const int lane = tid & 63;
  const int w = tid >> 6;
  const int r16 = lane & 15, g = lane >> 4;
  const int qt = blockIdx.x;   // q tile (64 rows)
  const int bh = blockIdx.y;   // b*16+h
  const size_t base = (size_t)bh * ST * SD;

  // Q fragments: A-layout, row = lane&15, k(d) = g*8 + 32*ks
  bf16x8 qf[2];
  {
    int qrow = qt * 64 + w * 16 + r16;
#pragma unroll
    for (int ks = 0; ks < 2; ++ks)
      qf[ks] = ld8(Q + base + (size_t)qrow * SD + ks * 32 + g * 8);
  }

  const int q_glob = qt * 64 + w * 16 + g * 4;  // + r gives this lane's q rows
  float mrow[4], lrow[4];
  f32x4 acc[4] = {};
#pragma unroll
  for (int r = 0; r < 4; ++r) { mrow[r] = -__builtin_inff(); lrow[r] = 0.f; }

  for (int kvt = 0; kvt <= qt; ++kvt) {
    __syncthreads();  // all waves done reading previous K/V tiles
#pragma unroll
    for (int it = 0; it < 2; ++it) {  // stage K tile [64][64]
      int c = it * 256 + tid;
      int row = c >> 3, cb = (c & 7) * 8;
      gll16(Kv + base + (size_t)(kvt * 64 + row) * SD + cb, Ks + c * 8);
    }
#pragma unroll
    for (int it = 0; it < 2; ++it) {  // stage V^T tile [64 d][64 t]
      int c = it * 256 + tid;
      int row = c >> 3, cb = (c & 7) * 8;
      gll16(VT + base + (size_t)row * ST + kvt * 64 + cb, Vs + c * 8);
    }
    __syncthreads();  // drains vmcnt -> tiles visible

    // S = Q K^T  (16 q x 64 t per wave)
    f32x4 s[4];
#pragma unroll
    for (int tt = 0; tt < 4; ++tt) {
      f32x4 z = {};
      bf16x8 kf0 = ld8(&Ks[(tt * 16 + r16) * 64 + g * 8]);
      bf16x8 kf1 = ld8(&Ks[(tt * 16 + r16) * 64 + 32 + g * 8]);
      z = MFMA16(qf[0], kf0, z);
      z = MFMA16(qf[1], kf1, z);
      s[tt] = z;
    }
    const bool diag = (kvt == qt);
#pragma unroll
    for (int tt = 0; tt < 4; ++tt)
#pragma unroll
      for (int r = 0; r < 4; ++r) {
        float v = s[tt][r] * 0.125f;
        if (diag && (kvt * 64 + tt * 16 + r16 > q_glob + r)) v = -__builtin_inff();
        s[tt][r] = v;
      }

    // per-row block max (reduce over 16 lanes of the t dimension)
    float bm[4];
#pragma unroll
    for (int r = 0; r < 4; ++r)
      bm[r] = fmaxf(fmaxf(s[0][r], s[1][r]), fmaxf(s[2][r], s[3][r]));
#pragma unroll
    for (int mask = 1; mask < 16; mask <<= 1)
#pragma unroll
      for (int r = 0; r < 4; ++r) bm[r] = fmaxf(bm[r], __shfl_xor(bm[r], mask, 64));

    float corr[4];
#pragma unroll
    for (int r = 0; r < 4; ++r) {
      float mn = fmaxf(mrow[r], bm[r]);
      corr[r] = __expf(mrow[r] - mn);  // first tile: exp(-inf)=0
      mrow[r] = mn;
    }

    // P = exp(S - m), accumulate row sums, stash P (bf16) in per-wave LDS
    float rsum[4] = {0.f, 0.f, 0.f, 0.f};
#pragma unroll
    for (int tt = 0; tt < 4; ++tt)
#pragma unroll
      for (int r = 0; r < 4; ++r) {
        float p = __expf(s[tt][r] - mrow[r]);
        rsum[r] += p;
        Ps[w][g * 4 + r][tt * 16 + r16] = f2bf(p);
      }
#pragma unroll
    for (int mask = 1; mask < 16; mask <<= 1)
#pragma unroll
      for (int r = 0; r < 4; ++r) rsum[r] += __shfl_xor(rsum[r], mask, 64);
#pragma unroll
    for (int r = 0; r < 4; ++r) lrow[r] = lrow[r] * corr[r] + rsum[r];

    // rescale accumulator
#pragma unroll
    for (int dt = 0; dt < 4; ++dt)
#pragma unroll
      for (int r = 0; r < 4; ++r) acc[dt][r] *= corr[r];

    // P A-fragments from per-wave LDS (wave-local; compiler inserts lgkm waits)
    bf16x8 pa[2];
#pragma unroll
    for (int ks = 0; ks < 2; ++ks) pa[ks] = ld8(&Ps[w][r16][ks * 32 + g * 8]);

    // PV: acc[dt] += P * V
#pragma unroll
    for (int dt = 0; dt < 4; ++dt) {
      bf16x8 v0 = ld8(&Vs[(dt * 16 + r16) * 64 + g * 8]);
      bf16x8 v1 = ld8(&Vs[(dt * 16 + r16) * 64 + 32 + g * 8]);
      acc[dt] = MFMA16(pa[0], v0, acc[dt]);
      acc[dt] = MFMA16(pa[1], v1, acc[dt]);
    }
  }

  // epilogue: Y[B,T,E] bf16, e = h*64 + d
  const int b = bh >> 4, h = bh & 15;
#pragma unroll
  for (int r = 0; r < 4; ++r) {
    float inv = 1.f / lrow[r];
#pragma unroll
    for (int dt = 0; dt < 4; ++dt) {
      int d = dt * 16 + r16;
      Y[((size_t)b * ST + q_glob + r) * SE + h * SD + d] = f2bf(acc[dt][r] * inv);
    }
  }
}

// ---- launch ----------------------------------------------------------------
extern "C" void kernel_launch(void* const* d_in, const int* in_sizes, int n_in,
                              void* d_out, int out_size, void* d_ws, size_t ws_size,
                              hipStream_t stream) {
  const float* x = (const float*)d_in[0];       // [4,2048,1024]
  const float* w_qkv = (const float*)d_in[1];   // [3072,1024]
  const float* w_out = (const float*)d_in[2];   // [1024,1024]
  float* out = (float*)d_out;                   // [4,2048,1024] f32

  const size_t NX = (size_t)SB * ST * SE;       // 8388608
  const size_t NQKV = (size_t)3 * SE * SE;      // 3145728
  const size_t NWO = (size_t)SE * SE;           // 1048576
  const size_t NHD = (size_t)SB * SH * ST * SD; // 8388608

  unsigned short* xb    = (unsigned short*)d_ws;        // 16MB, reused as Y later
  unsigned short* wqkvb = xb + NX;                      // 6MB
  unsigned short* woutb = wqkvb + NQKV;                 // 2MB
  unsigned short* q     = woutb + NWO;                  // 16MB
  unsigned short* k     = q + NHD;                      // 16MB
  unsigned short* vT    = k + NHD;                      // 16MB
  unsigned short* y     = xb;                           // alias (xb dead after GEMM1)

  cvt_f32_bf16<<<(int)(NX / 4 + 255) / 256, 256, 0, stream>>>(x, xb, (int)(NX / 4));
  cvt_f32_bf16<<<(int)(NQKV / 4 + 255) / 256, 256, 0, stream>>>(w_qkv, wqkvb, (int)(NQKV / 4));
  cvt_f32_bf16<<<(int)(NWO / 4 + 255) / 256, 256, 0, stream>>>(w_out, woutb, (int)(NWO / 4));

  // qkv = x @ w_qkv^T, scattered into Q/K/VT
  gemm_nt<1><<<dim3(3 * SE / 128, SB * ST / 128), 256, 0, stream>>>(
      xb, wqkvb, nullptr, q, k, vT, SB * ST, 3 * SE, SE);

  attn_causal<<<dim3(ST / 64, SB * SH), 256, 0, stream>>>(q, k, vT, y);

  // out = y @ w_out^T (f32 out)
  gemm_nt<0><<<dim3(SE / 128, SB * ST / 128), 256, 0, stream>>>(
      y, woutb, out, nullptr, nullptr, nullptr, SB * ST, SE, SE);
}

// Round 2
// 322.017 us; speedup vs baseline: 1.2218x; 1.2218x over previous
//
#include <hip/hip_runtime.h>

// ---- types / helpers -------------------------------------------------------
typedef __bf16 bf16x8 __attribute__((ext_vector_type(8)));
typedef float f32x4 __attribute__((ext_vector_type(4)));
typedef unsigned short ushortx8 __attribute__((ext_vector_type(8)));
typedef unsigned short ushortx4 __attribute__((ext_vector_type(4)));

#define DEVI static __device__ __forceinline__

DEVI unsigned short f2bf(float f) {  // round-to-nearest-even f32 -> bf16
  unsigned int u = __builtin_bit_cast(unsigned int, f);
  u += 0x7FFFu + ((u >> 16) & 1u);
  return (unsigned short)(u >> 16);
}

DEVI bf16x8 ld8(const unsigned short* p) {  // 16B vector load (global or LDS)
  return __builtin_bit_cast(bf16x8, *(const ushortx8*)p);
}

DEVI void gll16(const unsigned short* g, unsigned short* l) {  // global->LDS 16B DMA
  __builtin_amdgcn_global_load_lds((const __attribute__((address_space(1))) void*)g,
                                   (__attribute__((address_space(3))) void*)l, 16, 0, 0);
}

#define MFMA16(a, b, c) __builtin_amdgcn_mfma_f32_16x16x32_bf16(a, b, c, 0, 0, 0)

// ---- problem constants -----------------------------------------------------
// B=4, T=2048, E=1024, H=16, D=64
#define SB 4
#define ST 2048
#define SE 1024
#define SH 16
#define SD 64

// ---- f32 -> bf16 convert ---------------------------------------------------
__global__ void cvt_f32_bf16(const float* __restrict__ in, unsigned short* __restrict__ out, int n4) {
  int i = blockIdx.x * blockDim.x + threadIdx.x;
  if (i >= n4) return;
  float4 v = ((const float4*)in)[i];
  ushortx4 o;
  o.x = f2bf(v.x); o.y = f2bf(v.y); o.z = f2bf(v.z); o.w = f2bf(v.w);
  ((ushortx4*)out)[i] = o;
}

// ---- NT GEMM: C[m,n] = sum_k A[m,k]*Bw[n,k], both bf16 K-contiguous --------
// 128x128 tile, BK=64, 4 waves (2x2), each wave 64x64 (4x4 MFMA frags).
// EPI==0: plain f32 store to Cf[M,N].
// EPI==1: scatter qkv -> Q[B,H,T,D], K[B,H,T,D], VT[B,H,D,T] in bf16.
template<int EPI>
__global__ __launch_bounds__(256, 2) void gemm_nt(
    const unsigned short* __restrict__ A, const unsigned short* __restrict__ Bw,
    float* __restrict__ Cf,
    unsigned short* __restrict__ Qo, unsigned short* __restrict__ Ko,
    unsigned short* __restrict__ VTo,
    int M, int N, int K) {
  __shared__ unsigned short As[128 * 64];
  __shared__ unsigned short Bs[128 * 64];
  const int tid = threadIdx.x;
  const int lane = tid & 63;
  const int w = tid >> 6;
  const int wr = w >> 1, wc = w & 1;
  const int r16 = lane & 15, g = lane >> 4;
  const int m0 = blockIdx.y * 128, n0 = blockIdx.x * 128;

  f32x4 acc[4][4] = {};

  for (int k0 = 0; k0 < K; k0 += 64) {
    __syncthreads();
#pragma unroll
    for (int it = 0; it < 4; ++it) {  // stage A tile [128][64]
      int c = it * 256 + tid;
      int row = c >> 3, cb = (c & 7) * 8;
      gll16(A + (size_t)(m0 + row) * K + k0 + cb, As + c * 8);
    }
#pragma unroll
    for (int it = 0; it < 4; ++it) {  // stage B tile [128][64]
      int c = it * 256 + tid;
      int row = c >> 3, cb = (c & 7) * 8;
      gll16(Bw + (size_t)(n0 + row) * K + k0 + cb, Bs + c * 8);
    }
    __syncthreads();
#pragma unroll
    for (int ks = 0; ks < 2; ++ks) {
      bf16x8 af[4], bfr[4];
#pragma unroll
      for (int mt = 0; mt < 4; ++mt)
        af[mt] = ld8(&As[(wr * 64 + mt * 16 + r16) * 64 + ks * 32 + g * 8]);
#pragma unroll
      for (int nt = 0; nt < 4; ++nt)
        bfr[nt] = ld8(&Bs[(wc * 64 + nt * 16 + r16) * 64 + ks * 32 + g * 8]);
#pragma unroll
      for (int mt = 0; mt < 4; ++mt)
#pragma unroll
        for (int nt = 0; nt < 4; ++nt)
          acc[mt][nt] = MFMA16(af[mt], bfr[nt], acc[mt][nt]);
    }
  }

  // epilogue: C frag layout col = lane&15, row = (lane>>4)*4 + r
#pragma unroll
  for (int mt = 0; mt < 4; ++mt) {
#pragma unroll
    for (int nt = 0; nt < 4; ++nt) {
#pragma unroll
      for (int r = 0; r < 4; ++r) {
        int m = m0 + wr * 64 + mt * 16 + g * 4 + r;
        int n = n0 + wc * 64 + nt * 16 + r16;
        float v = acc[mt][nt][r];
        if (EPI == 0) {
          Cf[(size_t)m * N + n] = v;
        } else {
          int b = m >> 11, t = m & (ST - 1);
          int which = n >> 10, h = (n >> 6) & (SH - 1), d = n & (SD - 1);
          int bh = b * SH + h;
          unsigned short hv = f2bf(v);
          if (which == 0)
            Qo[((size_t)bh * ST + t) * SD + d] = hv;
          else if (which == 1)
            Ko[((size_t)bh * ST + t) * SD + d] = hv;
          else
            VTo[((size_t)bh * SD + d) * ST + t] = hv;
        }
      }
    }
  }
}

// ---- causal flash attention v2 ---------------------------------------------
// QBLK=128 (4 waves x 32 q-rows), KVBLK=64, double-buffered K/V with XOR
// swizzle (byte ^= (row&7)<<4, pre-swizzled global source per rule 21).
// grid: (T/128, B*H); heavy tiles dispatched first.

// stage one 64x64 bf16 tile: linear LDS dest, source col pre-swizzled
DEVI void stage_tile(const unsigned short* gbase, size_t rowstride,
                     unsigned short* lds, int tid) {
#pragma unroll
  for (int it = 0; it < 2; ++it) {
    int c = it * 256 + tid;
    int row = c >> 3, j = c & 7;
    int src = ((j * 16) ^ ((row & 7) << 4)) >> 1;  // shorts
    gll16(gbase + (size_t)row * rowstride + src, lds + c * 8);
  }
}

DEVI bf16x8 ldswz(const unsigned short* L, int row, int colsh) {  // swizzled read
  return ld8(L + row * 64 + ((((colsh * 2) ^ ((row & 7) << 4))) >> 1));
}

__global__ __launch_bounds__(256, 3) void attn_causal(
    const unsigned short* __restrict__ Q, const unsigned short* __restrict__ Kv,
    const unsigned short* __restrict__ VT, unsigned short* __restrict__ Y) {
  __shared__ unsigned short Ks[2][64 * 64];   // [t][d], swizzled
  __shared__ unsigned short Vs[2][64 * 64];   // [d][t], swizzled
  __shared__ __align__(16) unsigned short Ps[4][32][72];  // per-wave P, pad 72

  const int tid = threadIdx.x;
  const int lane = tid & 63;
  const int w = tid >> 6;
  const int r16 = lane & 15, g = lane >> 4;
  const int qt = (ST / 128 - 1) - blockIdx.x;  // heavy blocks first
  const int bh = blockIdx.y;                   // b*16+h
  const size_t base = (size_t)bh * ST * SD;

  // Q fragments: A-layout row = lane&15, k(d) = g*8 + 32*ks ; 2 m-frags/wave
  bf16x8 qf[2][2];
#pragma unroll
  for (int mq = 0; mq < 2; ++mq) {
    int qrow = qt * 128 + w * 32 + mq * 16 + r16;
#pragma unroll
    for (int ks = 0; ks < 2; ++ks)
      qf[mq][ks] = ld8(Q + base + (size_t)qrow * SD + ks * 32 + g * 8);
  }

  const int q_base = qt * 128 + w * 32 + g * 4;  // + mq*16 + r = this lane's rows
  float mrow[2][4], lrow[2][4];
  f32x4 acc[2][4] = {};
#pragma unroll
  for (int mq = 0; mq < 2; ++mq)
#pragma unroll
    for (int r = 0; r < 4; ++r) { mrow[mq][r] = -__builtin_inff(); lrow[mq][r] = 0.f; }

  const int nkv = 2 * qt + 2;
  // prologue: stage tile 0 into buffer 0
  stage_tile(Kv + base, SD, Ks[0], tid);
  stage_tile(VT + base, ST, Vs[0], tid);
  __syncthreads();

  for (int kvt = 0; kvt < nkv; ++kvt) {
    const int cur = kvt & 1;
    if (kvt + 1 < nkv) {  // prefetch next tile into other buffer
      stage_tile(Kv + base + (size_t)(kvt + 1) * 64 * SD, SD, Ks[cur ^ 1], tid);
      stage_tile(VT + base + (kvt + 1) * 64, ST, Vs[cur ^ 1], tid);
    }

    // S = Q K^T  (32 q x 64 t per wave)
    f32x4 s[2][4];
    __builtin_amdgcn_s_setprio(1);
#pragma unroll
    for (int tt = 0; tt < 4; ++tt) {
      bf16x8 kf0 = ldswz(Ks[cur], tt * 16 + r16, g * 8);
      bf16x8 kf1 = ldswz(Ks[cur], tt * 16 + r16, 32 + g * 8);
#pragma unroll
      for (int mq = 0; mq < 2; ++mq) {
        f32x4 z = {};
        z = MFMA16(qf[mq][0], kf0, z);
        z = MFMA16(qf[mq][1], kf1, z);
        s[mq][tt] = z;
      }
    }
    __builtin_amdgcn_s_setprio(0);

#pragma unroll
    for (int mq = 0; mq < 2; ++mq)
#pragma unroll
      for (int tt = 0; tt < 4; ++tt)
#pragma unroll
        for (int r = 0; r < 4; ++r) s[mq][tt][r] *= 0.125f;

    if (kvt >= 2 * qt) {  // diagonal tiles: causal mask (wave-uniform branch)
#pragma unroll
      for (int mq = 0; mq < 2; ++mq)
#pragma unroll
        for (int tt = 0; tt < 4; ++tt)
#pragma unroll
          for (int r = 0; r < 4; ++r)
            if (kvt * 64 + tt * 16 + r16 > q_base + mq * 16 + r)
              s[mq][tt][r] = -__builtin_inff();
    }

    // per-row block max (reduce over 16 lanes = t dimension)
    float bm[2][4];
#pragma unroll
    for (int mq = 0; mq < 2; ++mq)
#pragma unroll
      for (int r = 0; r < 4; ++r)
        bm[mq][r] = fmaxf(fmaxf(s[mq][0][r], s[mq][1][r]), fmaxf(s[mq][2][r], s[mq][3][r]));
#pragma unroll
    for (int mask = 1; mask < 16; mask <<= 1)
#pragma unroll
      for (int mq = 0; mq < 2; ++mq)
#pragma unroll
        for (int r = 0; r < 4; ++r) bm[mq][r] = fmaxf(bm[mq][r], __shfl_xor(bm[mq][r], mask, 64));

    float corr[2][4];
#pragma unroll
    for (int mq = 0; mq < 2; ++mq)
#pragma unroll
      for (int r = 0; r < 4; ++r) {
        float mn = fmaxf(mrow[mq][r], bm[mq][r]);
        corr[mq][r] = __expf(mrow[mq][r] - mn);  // first tile: exp(-inf)=0
        mrow[mq][r] = mn;
      }

    // P = exp(S - m), row sums, stash P (bf16) in per-wave LDS
    float rsum[2][4] = {};
#pragma unroll
    for (int mq = 0; mq < 2; ++mq)
#pragma unroll
      for (int tt = 0; tt < 4; ++tt)
#pragma unroll
        for (int r = 0; r < 4; ++r) {
          float p = __expf(s[mq][tt][r] - mrow[mq][r]);
          rsum[mq][r] += p;
          Ps[w][mq * 16 + g * 4 + r][tt * 16 + r16] = f2bf(p);
        }
#pragma unroll
    for (int mask = 1; mask < 16; mask <<= 1)
#pragma unroll
      for (int mq = 0; mq < 2; ++mq)
#pragma unroll
        for (int r = 0; r < 4; ++r) rsum[mq][r] += __shfl_xor(rsum[mq][r], mask, 64);
#pragma unroll
    for (int mq = 0; mq < 2; ++mq)
#pragma unroll
      for (int r = 0; r < 4; ++r) lrow[mq][r] = lrow[mq][r] * corr[mq][r] + rsum[mq][r];

    // rescale accumulator
#pragma unroll
    for (int mq = 0; mq < 2; ++mq)
#pragma unroll
      for (int dt = 0; dt < 4; ++dt)
#pragma unroll
        for (int r = 0; r < 4; ++r) acc[mq][dt][r] *= corr[mq][r];

    // P A-fragments from per-wave LDS (wave-local, in-order DS => safe)
    bf16x8 pa[2][2];
#pragma unroll
    for (int mq = 0; mq < 2; ++mq)
#pragma unroll
      for (int ks = 0; ks < 2; ++ks)
        pa[mq][ks] = ld8(&Ps[w][mq * 16 + r16][ks * 32 + g * 8]);

    // PV: acc[mq][dt] += P * V
    __builtin_amdgcn_s_setprio(1);
#pragma unroll
    for (int dt = 0; dt < 4; ++dt) {
      bf16x8 v0 = ldswz(Vs[cur], dt * 16 + r16, g * 8);
      bf16x8 v1 = ldswz(Vs[cur], dt * 16 + r16, 32 + g * 8);
#pragma unroll
      for (int mq = 0; mq < 2; ++mq) {
        acc[mq][dt] = MFMA16(pa[mq][0], v0, acc[mq][dt]);
        acc[mq][dt] = MFMA16(pa[mq][1], v1, acc[mq][dt]);
      }
    }
    __builtin_amdgcn_s_setprio(0);

    __syncthreads();  // drains vmcnt (next tile staged) + guards buffer reuse
  }

  // epilogue: Y[B,T,E] bf16, e = h*64 + d
  const int b = bh >> 4, h = bh & 15;
#pragma unroll
  for (int mq = 0; mq < 2; ++mq)
#pragma unroll
    for (int r = 0; r < 4; ++r) {
      float inv = 1.f / lrow[mq][r];
#pragma unroll
      for (int dt = 0; dt < 4; ++dt) {
        int d = dt * 16 + r16;
        Y[((size_t)b * ST + q_base + mq * 16 + r) * SE + h * SD + d] = f2bf(acc[mq][dt][r] * inv);
      }
    }
}

// ---- launch ----------------------------------------------------------------
extern "C" void kernel_launch(void* const* d_in, const int* in_sizes, int n_in,
                              void* d_out, int out_size, void* d_ws, size_t ws_size,
                              hipStream_t stream) {
  const float* x = (const float*)d_in[0];       // [4,2048,1024]
  const float* w_qkv = (const float*)d_in[1];   // [3072,1024]
  const float* w_out = (const float*)d_in[2];   // [1024,1024]
  float* out = (float*)d_out;                   // [4,2048,1024] f32

  const size_t NX = (size_t)SB * ST * SE;       // 8388608
  const size_t NQKV = (size_t)3 * SE * SE;      // 3145728
  const size_t NWO = (size_t)SE * SE;           // 1048576
  const size_t NHD = (size_t)SB * SH * ST * SD; // 8388608

  unsigned short* xb    = (unsigned short*)d_ws;        // 16MB, reused as Y later
  unsigned short* wqkvb = xb + NX;                      // 6MB
  unsigned short* woutb = wqkvb + NQKV;                 // 2MB
  unsigned short* q     = woutb + NWO;                  // 16MB
  unsigned short* k     = q + NHD;                      // 16MB
  unsigned short* vT    = k + NHD;                      // 16MB
  unsigned short* y     = xb;                           // alias (xb dead after GEMM1)

  cvt_f32_bf16<<<(int)(NX / 4 + 255) / 256, 256, 0, stream>>>(x, xb, (int)(NX / 4));
  cvt_f32_bf16<<<(int)(NQKV / 4 + 255) / 256, 256, 0, stream>>>(w_qkv, wqkvb, (int)(NQKV / 4));
  cvt_f32_bf16<<<(int)(NWO / 4 + 255) / 256, 256, 0, stream>>>(w_out, woutb, (int)(NWO / 4));

  // qkv = x @ w_qkv^T, scattered into Q/K/VT
  gemm_nt<1><<<dim3(3 * SE / 128, SB * ST / 128), 256, 0, stream>>>(
      xb, wqkvb, nullptr, q, k, vT, SB * ST, 3 * SE, SE);

  attn_causal<<<dim3(ST / 128, SB * SH), 256, 0, stream>>>(q, k, vT, y);

  // out = y @ w_out^T (f32 out)
  gemm_nt<0><<<dim3(SE / 128, SB * ST / 128), 256, 0, stream>>>(
      y, woutb, out, nullptr, nullptr, nullptr, SB * ST, SE, SE);
}

// Round 3
// 265.804 us; speedup vs baseline: 1.4802x; 1.2115x over previous
//
#include <hip/hip_runtime.h>

// ---- types / helpers -------------------------------------------------------
typedef __bf16 bf16x8 __attribute__((ext_vector_type(8)));
typedef __bf16 bf16x4 __attribute__((ext_vector_type(4)));
typedef float f32x4 __attribute__((ext_vector_type(4)));
typedef unsigned short ushortx8 __attribute__((ext_vector_type(8)));
typedef unsigned short ushortx4 __attribute__((ext_vector_type(4)));

#define DEVI static __device__ __forceinline__

DEVI unsigned short f2bf(float f) {  // round-to-nearest-even f32 -> bf16
  unsigned int u = __builtin_bit_cast(unsigned int, f);
  u += 0x7FFFu + ((u >> 16) & 1u);
  return (unsigned short)(u >> 16);
}

DEVI bf16x8 ld8(const unsigned short* p) {  // 16B vector load (global or LDS)
  return __builtin_bit_cast(bf16x8, *(const ushortx8*)p);
}

DEVI void gll16(const unsigned short* g, unsigned short* l) {  // global->LDS 16B DMA
  __builtin_amdgcn_global_load_lds((const __attribute__((address_space(1))) void*)g,
                                   (__attribute__((address_space(3))) void*)l, 16, 0, 0);
}

#define MFMA16(a, b, c) __builtin_amdgcn_mfma_f32_16x16x32_bf16(a, b, c, 0, 0, 0)

// ---- problem constants -----------------------------------------------------
// B=4, T=2048, E=1024, H=16, D=64
#define SB 4
#define ST 2048
#define SE 1024
#define SH 16
#define SD 64
#define QSCALE 0.18033688011112042f  /* 0.125 * log2(e): Q pre-scale for exp2 softmax */
#define DMTHR 11.541560327111708f    /* defer-max threshold: 8 * log2(e) */

// ---- f32 -> bf16 convert ---------------------------------------------------
__global__ void cvt_f32_bf16(const float* __restrict__ in, unsigned short* __restrict__ out, int n4) {
  int i = blockIdx.x * blockDim.x + threadIdx.x;
  if (i >= n4) return;
  float4 v = ((const float4*)in)[i];
  ushortx4 o;
  o.x = f2bf(v.x); o.y = f2bf(v.y); o.z = f2bf(v.z); o.w = f2bf(v.w);
  ((ushortx4*)out)[i] = o;
}

// ---- NT GEMM: C[m,n] = sum_k A[m,k]*Bw[n,k], both bf16 K-contiguous --------
// 128x128 tile, BK=64, 4 waves (2x2), each wave 64x64 (4x4 MFMA frags).
// EPI==0: plain f32 store to Cf[M,N].
// EPI==1: scatter qkv -> Q[B,H,T,D] (pre-scaled by QSCALE), K[B,H,T,D],
//         VT[B,H,D,T] in bf16.
template<int EPI>
__global__ __launch_bounds__(256, 2) void gemm_nt(
    const unsigned short* __restrict__ A, const unsigned short* __restrict__ Bw,
    float* __restrict__ Cf,
    unsigned short* __restrict__ Qo, unsigned short* __restrict__ Ko,
    unsigned short* __restrict__ VTo,
    int M, int N, int K) {
  __shared__ unsigned short As[128 * 64];
  __shared__ unsigned short Bs[128 * 64];
  const int tid = threadIdx.x;
  const int lane = tid & 63;
  const int w = tid >> 6;
  const int wr = w >> 1, wc = w & 1;
  const int r16 = lane & 15, g = lane >> 4;
  const int m0 = blockIdx.y * 128, n0 = blockIdx.x * 128;

  f32x4 acc[4][4] = {};

  for (int k0 = 0; k0 < K; k0 += 64) {
    __syncthreads();
#pragma unroll
    for (int it = 0; it < 4; ++it) {  // stage A tile [128][64]
      int c = it * 256 + tid;
      int row = c >> 3, cb = (c & 7) * 8;
      gll16(A + (size_t)(m0 + row) * K + k0 + cb, As + c * 8);
    }
#pragma unroll
    for (int it = 0; it < 4; ++it) {  // stage B tile [128][64]
      int c = it * 256 + tid;
      int row = c >> 3, cb = (c & 7) * 8;
      gll16(Bw + (size_t)(n0 + row) * K + k0 + cb, Bs + c * 8);
    }
    __syncthreads();
#pragma unroll
    for (int ks = 0; ks < 2; ++ks) {
      bf16x8 af[4], bfr[4];
#pragma unroll
      for (int mt = 0; mt < 4; ++mt)
        af[mt] = ld8(&As[(wr * 64 + mt * 16 + r16) * 64 + ks * 32 + g * 8]);
#pragma unroll
      for (int nt = 0; nt < 4; ++nt)
        bfr[nt] = ld8(&Bs[(wc * 64 + nt * 16 + r16) * 64 + ks * 32 + g * 8]);
#pragma unroll
      for (int mt = 0; mt < 4; ++mt)
#pragma unroll
        for (int nt = 0; nt < 4; ++nt)
          acc[mt][nt] = MFMA16(af[mt], bfr[nt], acc[mt][nt]);
    }
  }

  // epilogue: C frag layout col = lane&15, row = (lane>>4)*4 + r
#pragma unroll
  for (int mt = 0; mt < 4; ++mt) {
#pragma unroll
    for (int nt = 0; nt < 4; ++nt) {
#pragma unroll
      for (int r = 0; r < 4; ++r) {
        int m = m0 + wr * 64 + mt * 16 + g * 4 + r;
        int n = n0 + wc * 64 + nt * 16 + r16;
        float v = acc[mt][nt][r];
        if (EPI == 0) {
          Cf[(size_t)m * N + n] = v;
        } else {
          int b = m >> 11, t = m & (ST - 1);
          int which = n >> 10, h = (n >> 6) & (SH - 1), d = n & (SD - 1);
          int bh = b * SH + h;
          if (which == 0)
            Qo[((size_t)bh * ST + t) * SD + d] = f2bf(v * QSCALE);
          else if (which == 1)
            Ko[((size_t)bh * ST + t) * SD + d] = f2bf(v);
          else
            VTo[((size_t)bh * SD + d) * ST + t] = f2bf(v);
        }
      }
    }
  }
}

// ---- causal flash attention v3 ---------------------------------------------
// QBLK=128 (4 waves x 32 q-rows), KVBLK=64, double-buffered K/V, XOR swizzle.
// Swapped-operand QK^T (S^T = mfma(K,Q)): each lane owns one q-row per mq ->
// in-register softmax (in-lane reduce + 2 shuffles), P^T written as b64,
// PV computes O^T = mfma(V^T, P^T). exp2-domain (Q pre-scaled), defer-max.

DEVI void stage_tile(const unsigned short* gbase, size_t rowstride,
                     unsigned short* lds, int tid) {
#pragma unroll
  for (int it = 0; it < 2; ++it) {
    int c = it * 256 + tid;
    int row = c >> 3, j = c & 7;
    int src = ((j * 16) ^ ((row & 7) << 4)) >> 1;  // shorts
    gll16(gbase + (size_t)row * rowstride + src, lds + c * 8);
  }
}

DEVI bf16x8 ldswz(const unsigned short* L, int row, int colsh) {  // swizzled read
  return ld8(L + row * 64 + ((((colsh * 2) ^ ((row & 7) << 4))) >> 1));
}

__global__ __launch_bounds__(256, 3) void attn_causal(
    const unsigned short* __restrict__ Q, const unsigned short* __restrict__ Kv,
    const unsigned short* __restrict__ VT, unsigned short* __restrict__ Y) {
  __shared__ unsigned short Ks[2][64 * 64];   // [t][d], swizzled
  __shared__ unsigned short Vs[2][64 * 64];   // [d][t], swizzled
  __shared__ __align__(16) unsigned short Ps[4][32][72];  // per-wave P^T as [q][t], pad 72

  const int tid = threadIdx.x;
  const int lane = tid & 63;
  const int w = tid >> 6;
  const int r16 = lane & 15, g = lane >> 4;
  const int g4 = g * 4;
  const int qt = (ST / 128 - 1) - blockIdx.x;  // heavy blocks first
  const int bh = blockIdx.y;                   // b*16+h
  const size_t base = (size_t)bh * ST * SD;

  // Q fragments (B-operand layout == A layout for this shape):
  // n-row = lane&15, k(d) = g*8 + 32*ks ; 2 q-frags (mq) per wave
  bf16x8 qf[2][2];
#pragma unroll
  for (int mq = 0; mq < 2; ++mq) {
    int qrow = qt * 128 + w * 32 + mq * 16 + r16;
#pragma unroll
    for (int ks = 0; ks < 2; ++ks)
      qf[mq][ks] = ld8(Q + base + (size_t)qrow * SD + ks * 32 + g * 8);
  }

  // this lane's q-row per mq:
  int qg[2];
  qg[0] = qt * 128 + w * 32 + r16;
  qg[1] = qg[0] + 16;

  float mrow[2] = {-__builtin_inff(), -__builtin_inff()};
  float lrow[2] = {0.f, 0.f};
  f32x4 acc[2][4] = {};  // O^T: [mq][dt], lane holds d = dt*16+g*4+r for q = qg[mq]

  const int nkv = 2 * qt + 2;
  stage_tile(Kv + base, SD, Ks[0], tid);
  stage_tile(VT + base, ST, Vs[0], tid);
  __syncthreads();

  for (int kvt = 0; kvt < nkv; ++kvt) {
    const int cur = kvt & 1;
    if (kvt + 1 < nkv) {  // prefetch next tile into other buffer
      stage_tile(Kv + base + (size_t)(kvt + 1) * 64 * SD, SD, Ks[cur ^ 1], tid);
      stage_tile(VT + base + (kvt + 1) * 64, ST, Vs[cur ^ 1], tid);
    }

    // S^T = K Q^T : s[mq][tt][r] at q = qg[mq], t = kvt*64 + tt*16 + g*4 + r
    f32x4 s[2][4];
    __builtin_amdgcn_s_setprio(1);
#pragma unroll
    for (int tt = 0; tt < 4; ++tt) {
      bf16x8 kf0 = ldswz(Ks[cur], tt * 16 + r16, g * 8);
      bf16x8 kf1 = ldswz(Ks[cur], tt * 16 + r16, 32 + g * 8);
#pragma unroll
      for (int mq = 0; mq < 2; ++mq) {
        f32x4 z = {};
        z = MFMA16(kf0, qf[mq][0], z);
        z = MFMA16(kf1, qf[mq][1], z);
        s[mq][tt] = z;
      }
    }
    __builtin_amdgcn_s_setprio(0);

    if (kvt >= 2 * qt) {  // diagonal tiles: causal mask (wave-uniform branch)
#pragma unroll
      for (int mq = 0; mq < 2; ++mq)
#pragma unroll
        for (int tt = 0; tt < 4; ++tt)
#pragma unroll
          for (int r = 0; r < 4; ++r)
            if (kvt * 64 + tt * 16 + g4 + r > qg[mq])
              s[mq][tt][r] = -__builtin_inff();
    }

    // per-q-row block max: in-lane over 16 regs, then 2 shuffles over g-groups
    float bm[2];
#pragma unroll
    for (int mq = 0; mq < 2; ++mq) {
      f32x4 m4;
#pragma unroll
      for (int r = 0; r < 4; ++r)
        m4[r] = fmaxf(fmaxf(s[mq][0][r], s[mq][1][r]), fmaxf(s[mq][2][r], s[mq][3][r]));
      bm[mq] = fmaxf(fmaxf(m4[0], m4[1]), fmaxf(m4[2], m4[3]));
    }
#pragma unroll
    for (int mq = 0; mq < 2; ++mq) {
      bm[mq] = fmaxf(bm[mq], __shfl_xor(bm[mq], 16, 64));
      bm[mq] = fmaxf(bm[mq], __shfl_xor(bm[mq], 32, 64));
    }

    // defer-max: rescale only if running max grew by more than DMTHR
    if (__any((bm[0] > mrow[0] + DMTHR) || (bm[1] > mrow[1] + DMTHR))) {
#pragma unroll
      for (int mq = 0; mq < 2; ++mq) {
        float mn = fmaxf(mrow[mq], bm[mq]);
        float corr = exp2f(mrow[mq] - mn);  // first tile: exp2(-inf)=0
        mrow[mq] = mn;
        lrow[mq] *= corr;
#pragma unroll
        for (int dt = 0; dt < 4; ++dt)
#pragma unroll
          for (int r = 0; r < 4; ++r) acc[mq][dt][r] *= corr;
      }
    }

    // P = exp2(S - m): in-lane row sum + 2 shuffles; stash P^T (bf16, b64 packs)
#pragma unroll
    for (int mq = 0; mq < 2; ++mq) {
      f32x4 a4 = {};
#pragma unroll
      for (int tt = 0; tt < 4; ++tt) {
#pragma unroll
        for (int r = 0; r < 4; ++r) {
          float p = exp2f(s[mq][tt][r] - mrow[mq]);
          s[mq][tt][r] = p;
          a4[r] += p;
        }
      }
      float rs = (a4[0] + a4[1]) + (a4[2] + a4[3]);
      rs += __shfl_xor(rs, 16, 64);
      rs += __shfl_xor(rs, 32, 64);
      lrow[mq] += rs;
#pragma unroll
      for (int tt = 0; tt < 4; ++tt) {
        bf16x4 pv;
#pragma unroll
        for (int r = 0; r < 4; ++r) pv[r] = (__bf16)s[mq][tt][r];
        *(ushortx4*)&Ps[w][mq * 16 + r16][tt * 16 + g4] = __builtin_bit_cast(ushortx4, pv);
      }
    }

    // P^T B-fragments (wave-local LDS, in-order DS => no barrier)
    bf16x8 pa[2][2];
#pragma unroll
    for (int mq = 0; mq < 2; ++mq)
#pragma unroll
      for (int ks = 0; ks < 2; ++ks)
        pa[mq][ks] = ld8(&Ps[w][mq * 16 + r16][ks * 32 + g * 8]);

    // O^T += V^T P^T
    __builtin_amdgcn_s_setprio(1);
#pragma unroll
    for (int dt = 0; dt < 4; ++dt) {
      bf16x8 v0 = ldswz(Vs[cur], dt * 16 + r16, g * 8);
      bf16x8 v1 = ldswz(Vs[cur], dt * 16 + r16, 32 + g * 8);
#pragma unroll
      for (int mq = 0; mq < 2; ++mq) {
        acc[mq][dt] = MFMA16(v0, pa[mq][0], acc[mq][dt]);
        acc[mq][dt] = MFMA16(v1, pa[mq][1], acc[mq][dt]);
      }
    }
    __builtin_amdgcn_s_setprio(0);

    __syncthreads();  // drains vmcnt (next tile staged) + guards buffer reuse
  }

  // epilogue: Y[B,T,E] bf16, e = h*64 + d; lane holds 4 consecutive d per dt
  const int b = bh >> 4, h = bh & 15;
#pragma unroll
  for (int mq = 0; mq < 2; ++mq) {
    float inv = 1.f / lrow[mq];
#pragma unroll
    for (int dt = 0; dt < 4; ++dt) {
      bf16x4 o;
#pragma unroll
      for (int r = 0; r < 4; ++r) o[r] = (__bf16)(acc[mq][dt][r] * inv);
      *(ushortx4*)&Y[((size_t)b * ST + qg[mq]) * SE + h * SD + dt * 16 + g4] =
          __builtin_bit_cast(ushortx4, o);
    }
  }
}

// ---- launch ----------------------------------------------------------------
extern "C" void kernel_launch(void* const* d_in, const int* in_sizes, int n_in,
                              void* d_out, int out_size, void* d_ws, size_t ws_size,
                              hipStream_t stream) {
  const float* x = (const float*)d_in[0];       // [4,2048,1024]
  const float* w_qkv = (const float*)d_in[1];   // [3072,1024]
  const float* w_out = (const float*)d_in[2];   // [1024,1024]
  float* out = (float*)d_out;                   // [4,2048,1024] f32

  const size_t NX = (size_t)SB * ST * SE;       // 8388608
  const size_t NQKV = (size_t)3 * SE * SE;      // 3145728
  const size_t NWO = (size_t)SE * SE;           // 1048576
  const size_t NHD = (size_t)SB * SH * ST * SD; // 8388608

  unsigned short* xb    = (unsigned short*)d_ws;        // 16MB, reused as Y later
  unsigned short* wqkvb = xb + NX;                      // 6MB
  unsigned short* woutb = wqkvb + NQKV;                 // 2MB
  unsigned short* q     = woutb + NWO;                  // 16MB
  unsigned short* k     = q + NHD;                      // 16MB
  unsigned short* vT    = k + NHD;                      // 16MB
  unsigned short* y     = xb;                           // alias (xb dead after GEMM1)

  cvt_f32_bf16<<<(int)(NX / 4 + 255) / 256, 256, 0, stream>>>(x, xb, (int)(NX / 4));
  cvt_f32_bf16<<<(int)(NQKV / 4 + 255) / 256, 256, 0, stream>>>(w_qkv, wqkvb, (int)(NQKV / 4));
  cvt_f32_bf16<<<(int)(NWO / 4 + 255) / 256, 256, 0, stream>>>(w_out, woutb, (int)(NWO / 4));

  // qkv = x @ w_qkv^T, scattered into Q/K/VT
  gemm_nt<1><<<dim3(3 * SE / 128, SB * ST / 128), 256, 0, stream>>>(
      xb, wqkvb, nullptr, q, k, vT, SB * ST, 3 * SE, SE);

  attn_causal<<<dim3(ST / 128, SB * SH), 256, 0, stream>>>(q, k, vT, y);

  // out = y @ w_out^T (f32 out)
  gemm_nt<0><<<dim3(SE / 128, SB * ST / 128), 256, 0, stream>>>(
      y, woutb, out, nullptr, nullptr, nullptr, SB * ST, SE, SE);
}

// Round 4
// 250.620 us; speedup vs baseline: 1.5698x; 1.0606x over previous
//
#include <hip/hip_runtime.h>

// ---- types / helpers -------------------------------------------------------
typedef __bf16 bf16x8 __attribute__((ext_vector_type(8)));
typedef __bf16 bf16x4 __attribute__((ext_vector_type(4)));
typedef __bf16 bf16x2 __attribute__((ext_vector_type(2)));
typedef float f32x4 __attribute__((ext_vector_type(4)));
typedef float f32x16 __attribute__((ext_vector_type(16)));
typedef unsigned short ushortx8 __attribute__((ext_vector_type(8)));
typedef unsigned short ushortx4 __attribute__((ext_vector_type(4)));
typedef unsigned int uint32x4v __attribute__((ext_vector_type(4)));

#define DEVI static __device__ __forceinline__

DEVI unsigned short f2bf(float f) {  // round-to-nearest-even f32 -> bf16
  unsigned int u = __builtin_bit_cast(unsigned int, f);
  u += 0x7FFFu + ((u >> 16) & 1u);
  return (unsigned short)(u >> 16);
}

DEVI bf16x8 ld8(const unsigned short* p) {  // 16B vector load (global or LDS)
  return __builtin_bit_cast(bf16x8, *(const ushortx8*)p);
}

DEVI void gll16(const unsigned short* g, unsigned short* l) {  // global->LDS 16B DMA
  __builtin_amdgcn_global_load_lds((const __attribute__((address_space(1))) void*)g,
                                   (__attribute__((address_space(3))) void*)l, 16, 0, 0);
}

#define MFMA16(a, b, c) __builtin_amdgcn_mfma_f32_16x16x32_bf16(a, b, c, 0, 0, 0)
#define MFMA32(a, b, c) __builtin_amdgcn_mfma_f32_32x32x16_bf16(a, b, c, 0, 0, 0)

DEVI unsigned pkbf(float lo, float hi) {  // pack 2 f32 -> u32 of 2 bf16 (lo in low16)
  bf16x2 v;
  v[0] = (__bf16)lo;
  v[1] = (__bf16)hi;
  return __builtin_bit_cast(unsigned, v);
}

DEVI float swaphalf_max(float x) {  // max(own, other-32-lane-half) for all lanes
  unsigned xu = __builtin_bit_cast(unsigned, x);
  auto pr = __builtin_amdgcn_permlane32_swap(xu, xu, false, false);
  return fmaxf(__builtin_bit_cast(float, (unsigned)pr[0]),
               __builtin_bit_cast(float, (unsigned)pr[1]));
}

DEVI float swaphalf_add(float x) {
  unsigned xu = __builtin_bit_cast(unsigned, x);
  auto pr = __builtin_amdgcn_permlane32_swap(xu, xu, false, false);
  return __builtin_bit_cast(float, (unsigned)pr[0]) +
         __builtin_bit_cast(float, (unsigned)pr[1]);
}

// ---- problem constants -----------------------------------------------------
// B=4, T=2048, E=1024, H=16, D=64
#define SB 4
#define ST 2048
#define SE 1024
#define SH 16
#define SD 64
#define QSCALE 0.18033688011112042f  /* 0.125 * log2(e): Q pre-scale for exp2 softmax */
#define DMTHR 11.541560327111708f    /* defer-max threshold: 8 * log2(e) */

// ---- f32 -> bf16 convert ---------------------------------------------------
__global__ void cvt_f32_bf16(const float* __restrict__ in, unsigned short* __restrict__ out, int n4) {
  int i = blockIdx.x * blockDim.x + threadIdx.x;
  if (i >= n4) return;
  float4 v = ((const float4*)in)[i];
  ushortx4 o;
  o.x = f2bf(v.x); o.y = f2bf(v.y); o.z = f2bf(v.z); o.w = f2bf(v.w);
  ((ushortx4*)out)[i] = o;
}

// ---- NT GEMM: C[m,n] = sum_k A[m,k]*Bw[n,k], both bf16 K-contiguous --------
// 128x128 tile, BK=64, 4 waves (2x2), each wave 64x64 (4x4 MFMA frags).
// EPI==0: plain f32 store to Cf[M,N].
// EPI==1: scatter qkv -> Q[B,H,T,D] (pre-scaled by QSCALE), K[B,H,T,D],
//         VT[B,H,D,T] in bf16.
template<int EPI>
__global__ __launch_bounds__(256, 2) void gemm_nt(
    const unsigned short* __restrict__ A, const unsigned short* __restrict__ Bw,
    float* __restrict__ Cf,
    unsigned short* __restrict__ Qo, unsigned short* __restrict__ Ko,
    unsigned short* __restrict__ VTo,
    int M, int N, int K) {
  __shared__ unsigned short As[128 * 64];
  __shared__ unsigned short Bs[128 * 64];
  const int tid = threadIdx.x;
  const int lane = tid & 63;
  const int w = tid >> 6;
  const int wr = w >> 1, wc = w & 1;
  const int r16 = lane & 15, g = lane >> 4;
  const int m0 = blockIdx.y * 128, n0 = blockIdx.x * 128;

  f32x4 acc[4][4] = {};

  for (int k0 = 0; k0 < K; k0 += 64) {
    __syncthreads();
#pragma unroll
    for (int it = 0; it < 4; ++it) {  // stage A tile [128][64]
      int c = it * 256 + tid;
      int row = c >> 3, cb = (c & 7) * 8;
      gll16(A + (size_t)(m0 + row) * K + k0 + cb, As + c * 8);
    }
#pragma unroll
    for (int it = 0; it < 4; ++it) {  // stage B tile [128][64]
      int c = it * 256 + tid;
      int row = c >> 3, cb = (c & 7) * 8;
      gll16(Bw + (size_t)(n0 + row) * K + k0 + cb, Bs + c * 8);
    }
    __syncthreads();
#pragma unroll
    for (int ks = 0; ks < 2; ++ks) {
      bf16x8 af[4], bfr[4];
#pragma unroll
      for (int mt = 0; mt < 4; ++mt)
        af[mt] = ld8(&As[(wr * 64 + mt * 16 + r16) * 64 + ks * 32 + g * 8]);
#pragma unroll
      for (int nt = 0; nt < 4; ++nt)
        bfr[nt] = ld8(&Bs[(wc * 64 + nt * 16 + r16) * 64 + ks * 32 + g * 8]);
#pragma unroll
      for (int mt = 0; mt < 4; ++mt)
#pragma unroll
        for (int nt = 0; nt < 4; ++nt)
          acc[mt][nt] = MFMA16(af[mt], bfr[nt], acc[mt][nt]);
    }
  }

  // epilogue: C frag layout col = lane&15, row = (lane>>4)*4 + r
#pragma unroll
  for (int mt = 0; mt < 4; ++mt) {
#pragma unroll
    for (int nt = 0; nt < 4; ++nt) {
#pragma unroll
      for (int r = 0; r < 4; ++r) {
        int m = m0 + wr * 64 + mt * 16 + g * 4 + r;
        int n = n0 + wc * 64 + nt * 16 + r16;
        float v = acc[mt][nt][r];
        if (EPI == 0) {
          Cf[(size_t)m * N + n] = v;
        } else {
          int b = m >> 11, t = m & (ST - 1);
          int which = n >> 10, h = (n >> 6) & (SH - 1), d = n & (SD - 1);
          int bh = b * SH + h;
          if (which == 0)
            Qo[((size_t)bh * ST + t) * SD + d] = f2bf(v * QSCALE);
          else if (which == 1)
            Ko[((size_t)bh * ST + t) * SD + d] = f2bf(v);
          else
            VTo[((size_t)bh * SD + d) * ST + t] = f2bf(v);
        }
      }
    }
  }
}

// ---- causal flash attention v4 ---------------------------------------------
// QBLK=128 (4 waves x 32 q-cols), KVBLK=64, double-buffered K/V, XOR swizzle.
// 32x32x16 MFMA, swapped operands: S^T = mfma(K, Q) puts q on cols -> each
// lane owns one q-row (lane&31), t split across lane-halves. Softmax fully
// in-register; P redistributed to PV B-fragments via permlane32_swap (T12).
// exp2-domain (Q pre-scaled), defer-max (T13).

DEVI void stage_tile(const unsigned short* gbase, size_t rowstride,
                     unsigned short* lds, int tid) {
#pragma unroll
  for (int it = 0; it < 2; ++it) {
    int c = it * 256 + tid;
    int row = c >> 3, j = c & 7;
    int src = ((j * 16) ^ ((row & 7) << 4)) >> 1;  // shorts
    gll16(gbase + (size_t)row * rowstride + src, lds + c * 8);
  }
}

DEVI bf16x8 ldswz(const unsigned short* L, int row, int colsh) {  // swizzled read
  return ld8(L + row * 64 + ((((colsh * 2) ^ ((row & 7) << 4))) >> 1));
}

__global__ __launch_bounds__(256, 4) void attn_causal(
    const unsigned short* __restrict__ Q, const unsigned short* __restrict__ Kv,
    const unsigned short* __restrict__ VT, unsigned short* __restrict__ Y) {
  __shared__ unsigned short Ks[2][64 * 64];   // [t][d], swizzled
  __shared__ unsigned short Vs[2][64 * 64];   // [d][t], swizzled

  const int tid = threadIdx.x;
  const int lane = tid & 63;
  const int w = tid >> 6;
  const int l5 = lane & 31, h = lane >> 5;
  const int qt = (ST / 128 - 1) - blockIdx.x;  // heavy blocks first
  const int bh = blockIdx.y;                   // b*16+head
  const size_t base = (size_t)bh * ST * SD;

  const int q_glob = qt * 128 + w * 32 + l5;   // this lane's q-row
  const int qwmin = qt * 128 + w * 32;         // wave q range [qwmin, qwmin+31]

  // Q B-fragments: col n = q = lane&31, k = h*8 + i, chained over kk (d-slices)
  bf16x8 qf[4];
#pragma unroll
  for (int kk = 0; kk < 4; ++kk)
    qf[kk] = ld8(Q + base + (size_t)q_glob * SD + kk * 16 + h * 8);

  float mrow = -__builtin_inff();
  float lrow = 0.f;
  f32x16 acc[2] = {};  // O^T: lane q=l5, d = dblk*32 + (reg&3) + 4h + 8*(reg>>2)

  const int nkv = 2 * qt + 2;
  stage_tile(Kv + base, SD, Ks[0], tid);
  stage_tile(VT + base, ST, Vs[0], tid);
  __syncthreads();

  for (int kvt = 0; kvt < nkv; ++kvt) {
    const int cur = kvt & 1;
    if (kvt + 1 < nkv) {  // prefetch next tile into other buffer
      stage_tile(Kv + base + (size_t)(kvt + 1) * 64 * SD, SD, Ks[cur ^ 1], tid);
      stage_tile(VT + base + (kvt + 1) * 64, ST, Vs[cur ^ 1], tid);
    }

    // tiles fully above this wave's q range contribute nothing
    const bool active = (kvt * 64) <= (qwmin + 31);
    if (active) {
      // S^T = K Q^T : two 32t x 32q blocks; lane owns q=l5, t-half per h
      f32x16 s0 = {}, s1 = {};
      __builtin_amdgcn_s_setprio(1);
#pragma unroll
      for (int kk = 0; kk < 4; ++kk) {
        bf16x8 k0 = ldswz(Ks[cur], l5, kk * 16 + h * 8);
        s0 = MFMA32(k0, qf[kk], s0);
      }
#pragma unroll
      for (int kk = 0; kk < 4; ++kk) {
        bf16x8 k1 = ldswz(Ks[cur], 32 + l5, kk * 16 + h * 8);
        s1 = MFMA32(k1, qf[kk], s1);
      }
      __builtin_amdgcn_s_setprio(0);

      if (kvt * 64 + 63 > qwmin) {  // diagonal overlap: causal mask
        const int t0 = kvt * 64 + 4 * h;
#pragma unroll
        for (int reg = 0; reg < 16; ++reg) {
          int t = t0 + (reg & 3) + 8 * (reg >> 2);
          if (t > q_glob) s0[reg] = -__builtin_inff();
          if (t + 32 > q_glob) s1[reg] = -__builtin_inff();
        }
      }

      // row max: elementwise + in-lane tree + one half-swap
      f32x16 mx;
#pragma unroll
      for (int i = 0; i < 16; ++i) mx[i] = fmaxf(s0[i], s1[i]);
#pragma unroll
      for (int i = 0; i < 8; ++i) mx[i] = fmaxf(mx[i], mx[i + 8]);
#pragma unroll
      for (int i = 0; i < 4; ++i) mx[i] = fmaxf(mx[i], mx[i + 4]);
      float bm = fmaxf(fmaxf(mx[0], mx[1]), fmaxf(mx[2], mx[3]));
      bm = swaphalf_max(bm);

      // defer-max: rescale only if running max grew by more than DMTHR
      if (__any(bm > mrow + DMTHR)) {
        float mn = fmaxf(mrow, bm);
        float corr = exp2f(mrow - mn);  // first tile: exp2(-inf)=0
        mrow = mn;
        lrow *= corr;
#pragma unroll
        for (int dblk = 0; dblk < 2; ++dblk)
#pragma unroll
          for (int i = 0; i < 16; ++i) acc[dblk][i] *= corr;
      }

      // P = exp2(S - m), in-lane sum + half-swap
#pragma unroll
      for (int i = 0; i < 16; ++i) {
        s0[i] = exp2f(s0[i] - mrow);
        s1[i] = exp2f(s1[i] - mrow);
      }
      f32x16 sm;
#pragma unroll
      for (int i = 0; i < 16; ++i) sm[i] = s0[i] + s1[i];
#pragma unroll
      for (int i = 0; i < 8; ++i) sm[i] += sm[i + 8];
#pragma unroll
      for (int i = 0; i < 4; ++i) sm[i] += sm[i + 4];
      float rs = (sm[0] + sm[1]) + (sm[2] + sm[3]);
      lrow += swaphalf_add(rs);

      // pack P -> bf16 PV B-fragments via permlane32_swap (no LDS roundtrip)
      bf16x8 pb[2][2];
      auto packblk = [&](const f32x16& S, bf16x8* out) {
        unsigned a = pkbf(S[0], S[1]), b2 = pkbf(S[2], S[3]);
        unsigned c = pkbf(S[4], S[5]), d2 = pkbf(S[6], S[7]);
        auto r0 = __builtin_amdgcn_permlane32_swap(a, c, false, false);
        auto r1 = __builtin_amdgcn_permlane32_swap(b2, d2, false, false);
        uint32x4v w0 = {(unsigned)r0[0], (unsigned)r1[0], (unsigned)r0[1], (unsigned)r1[1]};
        out[0] = __builtin_bit_cast(bf16x8, w0);
        unsigned e = pkbf(S[8], S[9]), f2 = pkbf(S[10], S[11]);
        unsigned g2 = pkbf(S[12], S[13]), h2 = pkbf(S[14], S[15]);
        auto r2 = __builtin_amdgcn_permlane32_swap(e, g2, false, false);
        auto r3 = __builtin_amdgcn_permlane32_swap(f2, h2, false, false);
        uint32x4v w1 = {(unsigned)r2[0], (unsigned)r3[0], (unsigned)r2[1], (unsigned)r3[1]};
        out[1] = __builtin_bit_cast(bf16x8, w1);
      };
      packblk(s0, pb[0]);
      packblk(s1, pb[1]);

      // O^T += V^T P^T : A = V^T (d rows), B = P^T (q cols)
      __builtin_amdgcn_s_setprio(1);
#pragma unroll
      for (int dblk = 0; dblk < 2; ++dblk)
#pragma unroll
        for (int tt = 0; tt < 2; ++tt)
#pragma unroll
          for (int sl = 0; sl < 2; ++sl) {
            bf16x8 va = ldswz(Vs[cur], dblk * 32 + l5, tt * 32 + sl * 16 + h * 8);
            acc[dblk] = MFMA32(va, pb[tt][sl], acc[dblk]);
          }
      __builtin_amdgcn_s_setprio(0);
    }

    __syncthreads();  // drains vmcnt (next tile staged) + guards buffer reuse
  }

  // epilogue: Y[B,T,E] bf16, e = head*64 + d; 4 consecutive d per reg-group
  const int b = bh >> 4, hd = bh & 15;
  const float inv = 1.f / lrow;
#pragma unroll
  for (int dblk = 0; dblk < 2; ++dblk)
#pragma unroll
    for (int rg = 0; rg < 4; ++rg) {
      bf16x4 o;
#pragma unroll
      for (int j = 0; j < 4; ++j) o[j] = (__bf16)(acc[dblk][rg * 4 + j] * inv);
      int d = dblk * 32 + rg * 8 + 4 * h;
      *(ushortx4*)&Y[((size_t)b * ST + q_glob) * SE + hd * SD + d] =
          __builtin_bit_cast(ushortx4, o);
    }
}

// ---- launch ----------------------------------------------------------------
extern "C" void kernel_launch(void* const* d_in, const int* in_sizes, int n_in,
                              void* d_out, int out_size, void* d_ws, size_t ws_size,
                              hipStream_t stream) {
  const float* x = (const float*)d_in[0];       // [4,2048,1024]
  const float* w_qkv = (const float*)d_in[1];   // [3072,1024]
  const float* w_out = (const float*)d_in[2];   // [1024,1024]
  float* out = (float*)d_out;                   // [4,2048,1024] f32

  const size_t NX = (size_t)SB * ST * SE;       // 8388608
  const size_t NQKV = (size_t)3 * SE * SE;      // 3145728
  const size_t NWO = (size_t)SE * SE;           // 1048576
  const size_t NHD = (size_t)SB * SH * ST * SD; // 8388608

  unsigned short* xb    = (unsigned short*)d_ws;        // 16MB, reused as Y later
  unsigned short* wqkvb = xb + NX;                      // 6MB
  unsigned short* woutb = wqkvb + NQKV;                 // 2MB
  unsigned short* q     = woutb + NWO;                  // 16MB
  unsigned short* k     = q + NHD;                      // 16MB
  unsigned short* vT    = k + NHD;                      // 16MB
  unsigned short* y     = xb;                           // alias (xb dead after GEMM1)

  cvt_f32_bf16<<<(int)(NX / 4 + 255) / 256, 256, 0, stream>>>(x, xb, (int)(NX / 4));
  cvt_f32_bf16<<<(int)(NQKV / 4 + 255) / 256, 256, 0, stream>>>(w_qkv, wqkvb, (int)(NQKV / 4));
  cvt_f32_bf16<<<(int)(NWO / 4 + 255) / 256, 256, 0, stream>>>(w_out, woutb, (int)(NWO / 4));

  // qkv = x @ w_qkv^T, scattered into Q/K/VT
  gemm_nt<1><<<dim3(3 * SE / 128, SB * ST / 128), 256, 0, stream>>>(
      xb, wqkvb, nullptr, q, k, vT, SB * ST, 3 * SE, SE);

  attn_causal<<<dim3(ST / 128, SB * SH), 256, 0, stream>>>(q, k, vT, y);

  // out = y @ w_out^T (f32 out)
  gemm_nt<0><<<dim3(SE / 128, SB * ST / 128), 256, 0, stream>>>(
      y, woutb, out, nullptr, nullptr, nullptr, SB * ST, SE, SE);
}